// Round 1
// 774.905 us; speedup vs baseline: 1.0693x; 1.0693x over previous
//
#include <hip/hip_runtime.h>
#include <hip/hip_bf16.h>

#define N_EXP   8
#define NTOK    2048   // B*S
#define TOTROWS 4096   // NTOK * TOP_K

typedef __hip_bfloat16 bf16;
typedef __attribute__((ext_vector_type(8))) short short8;   // 8 bf16 (4 VGPRs)
typedef __attribute__((ext_vector_type(4))) float floatx4;  // MFMA acc

#define TN 128
#define TK 32
#define LDAB 40   // padded bf16 row stride for LDS tiles (80B: 16B-aligned, 2-way max)

// ---------------- helpers ----------------

__device__ inline float gelu_f(float v) {
    return 0.5f * v * (1.0f + erff(v * 0.70710678118654752440f));
}

__device__ inline float block_sum256(float v, float* red) {
    #pragma unroll
    for (int off = 32; off > 0; off >>= 1)
        v += __shfl_down(v, off, 64);
    __syncthreads();
    if ((threadIdx.x & 63) == 0) red[threadIdx.x >> 6] = v;
    __syncthreads();
    return red[0] + red[1] + red[2] + red[3];
}

__device__ inline unsigned rotl32(unsigned v, int d) { return (v << d) | (v >> (32 - d)); }

// JAX threefry2x32, key = (k0,k1)
__device__ inline void threefry2x32(unsigned k0, unsigned k1, unsigned x0, unsigned x1,
                                    unsigned& o0, unsigned& o1) {
    unsigned ks2 = k0 ^ k1 ^ 0x1BD11BDAu;
    x0 += k0; x1 += k1;
#define TF_R(r) { x0 += x1; x1 = rotl32(x1, r); x1 ^= x0; }
    TF_R(13) TF_R(15) TF_R(26) TF_R(6)
    x0 += k1; x1 += ks2 + 1u;
    TF_R(17) TF_R(29) TF_R(16) TF_R(24)
    x0 += ks2; x1 += k0 + 2u;
    TF_R(13) TF_R(15) TF_R(26) TF_R(6)
    x0 += k0; x1 += k1 + 3u;
    TF_R(17) TF_R(29) TF_R(16) TF_R(24)
    x0 += k1; x1 += ks2 + 4u;
    TF_R(13) TF_R(15) TF_R(26) TF_R(6)
    x0 += ks2; x1 += k0 + 5u;
#undef TF_R
    o0 = x0; o1 = x1;
}

__device__ inline int expert_of(int r, const int* bases) {
    int e = 0;
    #pragma unroll
    for (int i = 1; i < N_EXP; ++i) if (r >= bases[i]) e = i;
    return e;
}

// ---------------- policy + routing ----------------

__global__ __launch_bounds__(256) void policy_k(
    const float* __restrict__ x, const float* __restrict__ pw1,
    const float* __restrict__ pb1, const float* __restrict__ pg1,
    const float* __restrict__ pbb1, const float* __restrict__ pw2,
    const float* __restrict__ pb2, int2* __restrict__ top2, int* __restrict__ counts)
{
    const int t = blockIdx.x;
    const int lid = threadIdx.x;
    __shared__ float xs[512];
    __shared__ float hb[256];
    __shared__ float red[4];
    __shared__ float sc[8];

    xs[lid]       = x[(long long)t * 512 + lid];
    xs[lid + 256] = x[(long long)t * 512 + 256 + lid];
    __syncthreads();

    float acc = pb1[lid];
    for (int d = 0; d < 512; ++d)
        acc = fmaf(xs[d], pw1[d * 256 + lid], acc);

    float s  = block_sum256(acc, red);
    float sq = block_sum256(acc * acc, red);
    float mean = s * (1.0f / 256.0f);
    float var  = sq * (1.0f / 256.0f) - mean * mean;
    float rstd = rsqrtf(var + 1e-5f);
    float hn = (acc - mean) * rstd * pg1[lid] + pbb1[lid];
    hb[lid] = gelu_f(hn);
    __syncthreads();

    if (lid < 8) {
        float lg = pb2[lid];
        for (int j = 0; j < 256; ++j)
            lg = fmaf(hb[j], pw2[j * 8 + lid], lg);
        // jax_threefry_partitionable path: bits = o0 ^ o1 of tf(key, 0, i)
        unsigned idx = (unsigned)t * 8u + (unsigned)lid;
        unsigned o0, o1;
        threefry2x32(0u, 42u, 0u, idx, o0, o1);
        unsigned bits = o0 ^ o1;
        float u = __uint_as_float((bits >> 9) | 0x3f800000u) - 1.0f;
        float gml = -logf(-logf(u + 1e-10f) + 1e-10f);
        sc[lid] = lg + gml;   // TEMP = 1
    }
    __syncthreads();
    if (lid == 0) {
        float b0 = -INFINITY; int i0 = 0;
        #pragma unroll
        for (int e = 0; e < 8; ++e) if (sc[e] > b0) { b0 = sc[e]; i0 = e; }
        float b1v = -INFINITY; int i1 = 0;
        #pragma unroll
        for (int e = 0; e < 8; ++e) if (e != i0 && sc[e] > b1v) { b1v = sc[e]; i1 = e; }
        top2[t] = make_int2(i0, i1);
        atomicAdd(&counts[i0], 1);
        atomicAdd(&counts[i1], 1);
    }
}

__global__ void prefix_k(const int* __restrict__ counts, int* __restrict__ cursor,
                         int* __restrict__ bases) {
    if (threadIdx.x == 0 && blockIdx.x == 0) {
        int s = 0;
        for (int e = 0; e < N_EXP; ++e) { bases[e] = s; cursor[e] = s; s += counts[e]; }
    }
}

__global__ __launch_bounds__(256) void scatter_k(const int2* __restrict__ top2,
                                                 int* __restrict__ cursor,
                                                 int* __restrict__ list) {
    int t = blockIdx.x * 256 + threadIdx.x;
    int2 p = top2[t];
    int pos = atomicAdd(&cursor[p.x], 1); list[pos] = t;
    pos     = atomicAdd(&cursor[p.y], 1); list[pos] = t;
}

// ---------------- x -> bf16 cast ----------------

__global__ __launch_bounds__(256) void cast_x_k(const float* __restrict__ x,
                                                bf16* __restrict__ xb) {
    int i = (blockIdx.x * 256 + threadIdx.x) * 4;
    float4 v = *(const float4*)(x + i);
    bf16 o[4] = { (bf16)v.x, (bf16)v.y, (bf16)v.z, (bf16)v.w };
    *(unsigned long long*)(xb + i) = *(unsigned long long*)o;
}

// ---------------- MFMA grouped GEMM (pipelined) ----------------
// C[rbase+m][n] = act(A[row][k] * W_e[k][n] + bias_e[n]); A bf16, W fp32->bf16.
// Software pipeline: LDS double-buffer, register prefetch distance 2 K-tiles,
// ONE barrier per K-step. Per iteration (pair of K-tiles):
//   issue load(k+2) -> compute buf0 -> write buf1(k+1) -> bar
//   issue load(k+3) -> compute buf1 -> write buf0(k+2) -> bar
// Writes always target the buffer NOT being read this half; the vmcnt wait at
// each ds_write is for loads issued ~2 K-steps earlier, so HBM latency hides
// under MFMA + ds_read.
// TMp: 128 for the big GEMMs (LDS-traffic-optimal), 64 for the grid-starved
// small-N GEMMs (Win/Wout) to double active blocks/CU.

template <typename CT, int TMp>
__global__ __launch_bounds__(256) void mgemm_k(
    const bf16* __restrict__ A, const int* __restrict__ gather,
    const float* __restrict__ W, long long westride,
    const float* __restrict__ bias, int bestride,
    CT* __restrict__ C, bf16* __restrict__ Cmir,
    const int* __restrict__ counts, const int* __restrict__ bases,
    int K, int N, int act)
{
    const int e   = blockIdx.z;
    const int cnt = counts[e];
    const int m0  = blockIdx.y * TMp;
    if (m0 >= cnt) return;
    const int rbase = bases[e];
    const int n0  = blockIdx.x * TN;
    const float* We = W + (long long)e * westride;

    constexpr int MI = TMp / 32;   // per-wave 16-row fragment count

    __shared__ __align__(16) unsigned short As[2][TMp * LDAB];  // [m][k] bf16 bits
    __shared__ __align__(16) unsigned short Bs[2][TN * LDAB];   // [n][k] bf16 bits

    const int tid  = threadIdx.x;
    const int lane = tid & 63;
    const int wv   = tid >> 6;
    const int wm   = (wv & 1) * (TMp / 2);
    const int wn   = (wv >> 1) * 64;
    const int q    = lane >> 4;
    const int ln   = lane & 15;

    // A staging coords: thread loads 8 bf16 (16B); 64 rows per round.
    const int ar = tid >> 2;
    const int ak = (tid & 3) * 8;
    long long arow0 = 0, arow1 = 0;
    {
        int r0 = m0 + ar; if (r0 > cnt - 1) r0 = cnt - 1;
        long long p0 = gather ? (long long)gather[rbase + r0] : (long long)(rbase + r0);
        arow0 = p0 * K;
        if (TMp == 128) {
            int r1 = m0 + 64 + ar; if (r1 > cnt - 1) r1 = cnt - 1;
            long long p1 = gather ? (long long)gather[rbase + r1] : (long long)(rbase + r1);
            arow1 = p1 * K;
        }
    }
    // B staging coords: thread owns one n column, 16 consecutive k values.
    const int bn  = (wv & 1) * 64 + lane;   // n within tile, 0..127
    const int bkb = (wv >> 1) * 16;         // k sub-base: 0 or 16
    const float* wcol = We + n0 + bn;

    floatx4 acc[MI][4];
    #pragma unroll
    for (int i = 0; i < MI; ++i)
        #pragma unroll
        for (int j = 0; j < 4; ++j)
            acc[i][j] = (floatx4){0.f, 0.f, 0.f, 0.f};

    // two named prefetch register sets (no runtime-indexed reg arrays)
    uint4 a0A = {0,0,0,0}, a1A = {0,0,0,0}, a0B = {0,0,0,0}, a1B = {0,0,0,0};
    float wA[16], wB[16];

    auto mg_load = [&](uint4& a0r, uint4& a1r, float (&wr)[16], int koff) {
        a0r = *(const uint4*)(A + arow0 + koff + ak);
        if (TMp == 128) a1r = *(const uint4*)(A + arow1 + koff + ak);
        const float* wp = wcol + (long long)(koff + bkb) * N;
        #pragma unroll
        for (int kk = 0; kk < 16; ++kk) wr[kk] = wp[(long long)kk * N];
    };
    auto mg_store = [&](const uint4& a0r, const uint4& a1r, const float (&wr)[16], int buf) {
        *(uint4*)(&As[buf][ar * LDAB + ak]) = a0r;
        if (TMp == 128) *(uint4*)(&As[buf][(64 + ar) * LDAB + ak]) = a1r;
        union { unsigned short us[8]; uint4 v; } p0, p1;
        #pragma unroll
        for (int kk = 0; kk < 8; ++kk) {
            bf16 b0 = (bf16)wr[kk];
            bf16 b1 = (bf16)wr[kk + 8];
            p0.us[kk] = *(unsigned short*)&b0;
            p1.us[kk] = *(unsigned short*)&b1;
        }
        *(uint4*)(&Bs[buf][bn * LDAB + bkb])     = p0.v;
        *(uint4*)(&Bs[buf][bn * LDAB + bkb + 8]) = p1.v;
    };
    auto mg_compute = [&](int buf) {
        short8 a_frag[MI], b_frag[4];
        #pragma unroll
        for (int i = 0; i < MI; ++i)
            a_frag[i] = *(const short8*)(&As[buf][(wm + i * 16 + ln) * LDAB + q * 8]);
        #pragma unroll
        for (int j = 0; j < 4; ++j)
            b_frag[j] = *(const short8*)(&Bs[buf][(wn + j * 16 + ln) * LDAB + q * 8]);
        #pragma unroll
        for (int i = 0; i < MI; ++i)
            #pragma unroll
            for (int j = 0; j < 4; ++j)
                acc[i][j] = __builtin_amdgcn_mfma_f32_16x16x32_bf16(
                    a_frag[i], b_frag[j], acc[i][j], 0, 0, 0);
    };

    // prologue: tile 0 -> LDS buf0, tile 1 -> regs B
    mg_load(a0A, a1A, wA, 0);
    mg_store(a0A, a1A, wA, 0);
    mg_load(a0B, a1B, wB, TK);
    __syncthreads();

    // main loop: K is a multiple of 64 (512/1024/2048)
    int k0 = 0;
    for (; k0 + 2 * TK < K; k0 += 2 * TK) {
        mg_load(a0A, a1A, wA, k0 + 2 * TK);   // prefetch k+2
        mg_compute(0);                        // consume tile k0
        mg_store(a0B, a1B, wB, 1);            // write tile k0+1 (loaded 2 steps ago)
        __syncthreads();
        mg_load(a0B, a1B, wB, k0 + 3 * TK);   // prefetch k+3 (k0+96 <= K-32, in bounds)
        mg_compute(1);                        // consume tile k0+1
        mg_store(a0A, a1A, wA, 0);            // write tile k0+2
        __syncthreads();
    }
    // epilogue: k0 == K-64; buf0 holds tile K-64, regs B hold tile K-32
    mg_compute(0);
    mg_store(a0B, a1B, wB, 1);
    __syncthreads();
    mg_compute(1);

    // epilogue: C/D layout col = lane&15, row = quad*4 + reg
    #pragma unroll
    for (int i = 0; i < MI; ++i) {
        int rbase_i = m0 + wm + i * 16 + q * 4;
        #pragma unroll
        for (int j = 0; j < 4; ++j) {
            int n = n0 + wn + j * 16 + ln;
            float bv = bias[e * bestride + n];
            #pragma unroll
            for (int rg = 0; rg < 4; ++rg) {
                int r = rbase_i + rg;
                if (r >= cnt) continue;
                float v = acc[i][j][rg] + bv;
                if (act) v = gelu_f(v);
                long long off = (long long)(rbase + r) * N + n;
                C[off] = (CT)v;
                if (Cmir) Cmir[off] = (bf16)v;
            }
        }
    }
}

// ---------------- LN + gate + residual (row-global), writes h fp32 + hb bf16 ----------------

__global__ __launch_bounds__(256) void lngate_k(
    float* __restrict__ h, bf16* __restrict__ hb, const float* __restrict__ h2,
    const float* __restrict__ ng, const float* __restrict__ nb,
    const float* __restrict__ gw, const int* __restrict__ bases, int l)
{
    const int r = blockIdx.x;
    const int e = expert_of(r, bases);
    const int lid = threadIdx.x;
    const float* hr  = h  + (long long)r * 1024;
    const float* h2r = h2 + (long long)r * 1024;
    const int off = (e * 2 + l) * 1024;
    __shared__ float red[4];

    float s = 0.f, sq = 0.f, dt = 0.f;
    float hv[4], h2v[4];
    #pragma unroll
    for (int i = 0; i < 4; ++i) {
        int j = lid + 256 * i;
        float a = h2r[j];
        float b = hr[j];
        hv[i] = b; h2v[i] = a;
        s += a; sq += a * a;
        dt = fmaf(b, gw[off + j], dt);
    }
    s  = block_sum256(s, red);
    sq = block_sum256(sq, red);
    dt = block_sum256(dt, red);
    float mean = s * (1.f / 1024.f);
    float rstd = rsqrtf(sq * (1.f / 1024.f) - mean * mean + 1e-5f);
    float gate = 1.f / (1.f + expf(-dt));
    float* hw  = h  + (long long)r * 1024;
    bf16*  hbw = hb + (long long)r * 1024;
    #pragma unroll
    for (int i = 0; i < 4; ++i) {
        int j = lid + 256 * i;
        float v = (h2v[i] - mean) * rstd * ng[off + j] + nb[off + j];
        float nh = hv[i] + gate * v;
        hw[j] = nh;
        hbw[j] = (bf16)nh;
    }
}

// ---------------- final LN(x + out) + combine ----------------

__global__ __launch_bounds__(256) void final_k(
    const float* __restrict__ x, const bf16* __restrict__ orow,
    const float* __restrict__ fng, const float* __restrict__ fnb,
    const int* __restrict__ bases, const int* __restrict__ list,
    float* __restrict__ out)
{
    const int r = blockIdx.x;
    const int e = expert_of(r, bases);
    const int t = list[r];
    const int lid = threadIdx.x;
    __shared__ float red[4];

    float y[2];
    float s = 0.f, sq = 0.f;
    #pragma unroll
    for (int i = 0; i < 2; ++i) {
        int j = lid + 256 * i;
        float v = x[(long long)t * 512 + j] + (float)orow[(long long)r * 512 + j];
        y[i] = v; s += v; sq += v * v;
    }
    s  = block_sum256(s, red);
    sq = block_sum256(sq, red);
    float mean = s * (1.f / 512.f);
    float rstd = rsqrtf(sq * (1.f / 512.f) - mean * mean + 1e-5f);
    #pragma unroll
    for (int i = 0; i < 2; ++i) {
        int j = lid + 256 * i;
        float v = (y[i] - mean) * rstd * fng[e * 512 + j] + fnb[e * 512 + j];
        atomicAdd(&out[(long long)t * 512 + j], v);
    }
}

// ---------------- launch ----------------

extern "C" void kernel_launch(void* const* d_in, const int* in_sizes, int n_in,
                              void* d_out, int out_size, void* d_ws, size_t ws_size,
                              hipStream_t stream) {
    const float* x    = (const float*)d_in[0];
    const float* pw1  = (const float*)d_in[1];
    const float* pb1  = (const float*)d_in[2];
    const float* pg1  = (const float*)d_in[3];
    const float* pbb1 = (const float*)d_in[4];
    const float* pw2  = (const float*)d_in[5];
    const float* pb2  = (const float*)d_in[6];
    const float* Win  = (const float*)d_in[7];
    const float* b_in = (const float*)d_in[8];
    const float* W1   = (const float*)d_in[9];
    const float* b1   = (const float*)d_in[10];
    const float* W2   = (const float*)d_in[11];
    const float* b2   = (const float*)d_in[12];
    const float* ng   = (const float*)d_in[13];
    const float* nb   = (const float*)d_in[14];
    const float* gw   = (const float*)d_in[15];
    const float* Wout = (const float*)d_in[16];
    const float* bout = (const float*)d_in[17];
    const float* fng  = (const float*)d_in[18];
    const float* fnb  = (const float*)d_in[19];
    float* out = (float*)d_out;
    (void)ws_size; (void)in_sizes; (void)n_in;

    char* ws = (char*)d_ws;
    int* counts = (int*)ws;        // 8 ints @ 0
    int* cursor = counts + 8;      // 8 ints @ 32
    int* bases  = cursor + 8;      // 8 ints @ 64
    int2* top2  = (int2*)(ws + 128);             // 16 KB
    int*  list  = (int*)(ws + 128 + 2048 * 8);   // 16 KB
    size_t o = 128 + 2048 * 8 + 4096 * 4;
    o = (o + 255) & ~(size_t)255;
    bf16*  xb   = (bf16*) (ws + o); o += (size_t)NTOK * 512 * 2;      //  2 MB
    float* h    = (float*)(ws + o); o += (size_t)TOTROWS * 1024 * 4;  // 16 MB
    bf16*  hb   = (bf16*) (ws + o); o += (size_t)TOTROWS * 1024 * 2;  //  8 MB
    bf16*  tb   = (bf16*) (ws + o); o += (size_t)TOTROWS * 2048 * 2;  // 16 MB
    float* h2   = (float*)(ws + o); o += (size_t)TOTROWS * 1024 * 4;  // 16 MB
    bf16*  orow = (bf16*) (ws + o); o += (size_t)TOTROWS * 512 * 2;   //  4 MB
    // total ~62 MB

    hipMemsetAsync(d_out, 0, (size_t)out_size * sizeof(float), stream);
    hipMemsetAsync(ws, 0, 64, stream);  // counts + cursor

    policy_k<<<NTOK, 256, 0, stream>>>(x, pw1, pb1, pg1, pbb1, pw2, pb2, top2, counts);
    prefix_k<<<1, 64, 0, stream>>>(counts, cursor, bases);
    scatter_k<<<NTOK / 256, 256, 0, stream>>>(top2, cursor, list);
    cast_x_k<<<NTOK * 512 / 1024, 256, 0, stream>>>(x, xb);

    // h (+hb) = gather(x) @ Win_e + b_in    [4096,512]x[512,1024]  -- TM=64 for blocks/CU
    mgemm_k<float, 64><<<dim3(8, 32, 8), 256, 0, stream>>>(
        xb, list, Win, (long long)512 * 1024, b_in, 1024, h, hb,
        counts, bases, 512, 1024, 0);

    for (int l = 0; l < 2; ++l) {
        // tb = gelu(hb @ W1_el + b1)        [4096,1024]x[1024,2048]
        mgemm_k<bf16, 128><<<dim3(16, 16, 8), 256, 0, stream>>>(
            hb, nullptr, W1 + (long long)l * 1024 * 2048, (long long)2 * 1024 * 2048,
            b1 + l * 2048, 2 * 2048, tb, (bf16*)nullptr,
            counts, bases, 1024, 2048, 1);
        // h2 = tb @ W2_el + b2              [4096,2048]x[2048,1024]
        mgemm_k<float, 128><<<dim3(8, 16, 8), 256, 0, stream>>>(
            tb, nullptr, W2 + (long long)l * 2048 * 1024, (long long)2 * 2048 * 1024,
            b2 + l * 1024, 2 * 1024, h2, (bf16*)nullptr,
            counts, bases, 2048, 1024, 0);
        // h += sigmoid(h . gw) * LN(h2); hb mirror
        lngate_k<<<TOTROWS, 256, 0, stream>>>(h, hb, h2, ng, nb, gw, bases, l);
    }

    // orow = hb @ Wout_e + bout             [4096,1024]x[1024,512]  -- TM=64
    mgemm_k<bf16, 64><<<dim3(4, 32, 8), 256, 0, stream>>>(
        hb, nullptr, Wout, (long long)1024 * 512, bout, 512, orow, (bf16*)nullptr,
        counts, bases, 1024, 512, 0);

    // out[t] += LN(x[t] + orow)
    final_k<<<TOTROWS, 256, 0, stream>>>(x, orow, fng, fnb, bases, list, out);
}